// Round 6
// baseline (337.240 us; speedup 1.0000x reference)
//
#include <hip/hip_runtime.h>
#include <hip/hip_bf16.h>

// Problem constants
constexpr int Bc = 32, Sc = 4096, Dc = 64, Pc = 8, STRIDEc = 4, Hc = 512;
constexpr int Tc = (Sc - Pc) / STRIDEc + 1;   // 1023
constexpr int Kc = Pc * Dc;                   // 512
constexpr float EPSc = 1e-6f;
constexpr int PITCH = 40;                     // bf16 LDS row pitch (80B -> 2-way banks = free)
constexpr size_t WT_BYTES = 512 * 512 * 2;    // 512 KB

typedef __bf16 bf16x8 __attribute__((ext_vector_type(8)));
typedef unsigned short ushort8 __attribute__((ext_vector_type(8)));
typedef float f32x4 __attribute__((ext_vector_type(4)));

__device__ __forceinline__ int n_tok_of(int len) {
    return (len >= Pc) ? ((len - Pc) / STRIDEc + 1) : 1;
}

// fp32 -> bf16 round-to-nearest-even
__device__ __forceinline__ unsigned short f2bf(float f) {
    unsigned u = __builtin_bit_cast(unsigned, f);
    u = (u + 0x7FFFu + ((u >> 16) & 1u)) >> 16;
    return (unsigned short)u;
}

// ---------------------------------------------------------------------------
// Prep: Wt_s[k0/32][n][k%32] = bf16(W[k][n])  (transposed, k-slice-packed),
// token_lengths, PLUS a cost-balanced tile schedule:
//   cost(tile) = clamp(ntok_b - t0, 0, 64)  (valid rows => GEMM work)
//   bucket-sort 512 tiles by cost desc; pair rank i with rank 511-i on the
//   CU-sharing slots (i, i+256)  => each CU gets ~one heavy + one light tile.
// With the fused kernel's row-proportional MFMA (ttmax), this cost model now
// matches the kernel's actual cost.
// ---------------------------------------------------------------------------
__global__ __launch_bounds__(256) void prep_kernel(
        const float* __restrict__ W, const int* __restrict__ lengths,
        unsigned short* __restrict__ Wt, int* __restrict__ sched,
        float* __restrict__ out_tl) {
    __shared__ float tile[32][33];
    const int k0 = blockIdx.x * 32, n0 = blockIdx.y * 32;
    const int r = threadIdx.x >> 3, c = (threadIdx.x & 7) * 4;
    const float4 v = *(const float4*)(W + (size_t)(k0 + r) * Hc + n0 + c);
    tile[c + 0][r] = v.x;
    tile[c + 1][r] = v.y;
    tile[c + 2][r] = v.z;
    tile[c + 3][r] = v.w;
    __syncthreads();
    ushort4 o;
    o.x = f2bf(tile[r][c + 0]);
    o.y = f2bf(tile[r][c + 1]);
    o.z = f2bf(tile[r][c + 2]);
    o.w = f2bf(tile[r][c + 3]);
    // slice = blockIdx.x; within slice: n-major, 32 k's per row
    *(ushort4*)(Wt + (size_t)blockIdx.x * (Hc * 32) + (size_t)(n0 + r) * 32 + c) = o;

    if (blockIdx.x == 0 && blockIdx.y == 0) {
        const int tid = threadIdx.x;
        __shared__ int sntok[32];
        __shared__ int scnt[65];
        __shared__ int soff[65];
        __shared__ int ssorted[512];
        if (tid < Bc) {
            const int nt = n_tok_of(lengths[tid]);
            sntok[tid] = nt;
            out_tl[tid] = (float)nt;
        }
        if (tid < 65) scnt[tid] = 0;
        __syncthreads();
        // tile id i: b = i&31, bx = i>>5, t0 = bx*64
#pragma unroll
        for (int i = tid; i < 512; i += 256) {
            int cst = sntok[i & 31] - (i >> 5) * 64;
            cst = cst < 0 ? 0 : (cst > 64 ? 64 : cst);
            atomicAdd(&scnt[64 - cst], 1);        // bucket 0 = heaviest
        }
        __syncthreads();
        if (tid == 0) {
            int acc = 0;
            for (int k = 0; k < 65; ++k) { soff[k] = acc; acc += scnt[k]; }
        }
        __syncthreads();
#pragma unroll
        for (int i = tid; i < 512; i += 256) {
            int cst = sntok[i & 31] - (i >> 5) * 64;
            cst = cst < 0 ? 0 : (cst > 64 ? 64 : cst);
            const int pos = atomicAdd(&soff[64 - cst], 1);
            ssorted[pos] = i;
        }
        __syncthreads();
        // slot s (s<256) gets rank s; slot s (>=256) gets rank 511-(s-256)
#pragma unroll
        for (int s = tid; s < 512; s += 256)
            sched[s] = (s < 256) ? ssorted[s] : ssorted[767 - s];
    }
}

// ---------------------------------------------------------------------------
// Fused: tokens-write + bf16-MFMA GEMM (BM=64 x BN=512) + bias + RMSNorm*scale.
// r5 structure (best measured) with two surgical deltas:
//  * Row-proportional MFMA: tt-subtiles whose 16 rows are all >= ntok have
//    zero A-rows -> their MFMA is skipped (acc stays 0; epilogue unchanged
//    produces the exact bias-only rows). Block-uniform ttmax guard; the
//    full-tile case (ttmax==4) stays branch-free.
//  * Token stores moved AFTER the commit barrier: the barrier's vmcnt(0)
//    drain no longer exposes store latency; stores get the prefetch+MFMA
//    section as slack before the next barrier's drain.
// ---------------------------------------------------------------------------
__global__ __launch_bounds__(256, 2) void fused_kernel(
        const float* __restrict__ x, const int* __restrict__ lengths,
        const unsigned short* __restrict__ Wt, const float* __restrict__ bias,
        const float* __restrict__ scale, const int* __restrict__ sched,
        float* __restrict__ hidden, float* __restrict__ tokens) {
    const int slot = (int)blockIdx.y * 16 + (int)blockIdx.x;  // HW linear id
    const int idx  = sched[slot];
    const int b    = idx & 31;
    const int t0   = (idx >> 5) * 64;
    const int len  = lengths[b];
    const int ntok = n_tok_of(len);
    const int tid  = threadIdx.x;

    float* tokb = tokens + (size_t)b * Tc * Kc;

    if (t0 >= ntok) {
        // ---- fast path: every row in this block is padding ----
        // hidden row = scale * b / rms(b)  (== GEMM path on zero rows)
        __shared__ float red[4];
        const int w = tid >> 6, lane = tid & 63;
        const float2 b2 = *(const float2*)(bias + tid * 2);
        float s = b2.x * b2.x + b2.y * b2.y;
#pragma unroll
        for (int off = 32; off; off >>= 1) s += __shfl_xor(s, off);
        if (lane == 0) red[w] = s;
        __syncthreads();
        const float rstd0 = rsqrtf((red[0] + red[1] + red[2] + red[3])
                                   * (1.0f / (float)Hc) + EPSc);
        const int c4 = (tid & 127) * 4;
        const f32x4 cvec = *(const f32x4*)(bias + c4) * rstd0
                         * *(const f32x4*)(scale + c4);
        const f32x4 z = {0.f, 0.f, 0.f, 0.f};
        float* hidb = hidden + ((size_t)b * Tc + t0) * Hc;
        float* tokp = tokb + (size_t)t0 * Kc;
        const int r0 = tid >> 7;                 // 0 or 1: two rows per pass
#pragma unroll 8
        for (int rr = r0; rr < 64; rr += 2) {
            if (t0 + rr < Tc) {
                __builtin_nontemporal_store(cvec, (f32x4*)(hidb + (size_t)rr * Hc + c4));
                __builtin_nontemporal_store(z,    (f32x4*)(tokp + (size_t)rr * Kc + c4));
            }
        }
        return;
    }

    __shared__ unsigned short As[64 * PITCH];    // As[r][k], bf16 (token tile)
    __shared__ unsigned short Bs[512 * PITCH];   // Bs[n][k], bf16 (Wt tile)
    __shared__ float ssbuf[4][64];

    const int w    = tid >> 6;
    const int lane = tid & 63;
    const int l15  = lane & 15;
    const int quad = lane >> 4;

    const int rows  = ntok - t0;                 // >= 1 here
    const int ttmax = (rows >= 64) ? 4 : ((rows + 15) >> 4);   // 1..4, uniform

    f32x4 acc[4][8];                             // [ttile][ctile]
#pragma unroll
    for (int tt = 0; tt < 4; ++tt)
#pragma unroll
        for (int ct = 0; ct < 8; ++ct) acc[tt][ct] = (f32x4){0.f, 0.f, 0.f, 0.f};

    const float* xb = x + (size_t)b * (Sc * Dc);

    // Per-thread staging coordinates (A: 2 float4 chunks; B: 8 ushort8 chunks)
    int   a_r[2], a_c[2];  bool a_tv[2], a_lv[2];  const float* a_src[2];
#pragma unroll
    for (int it = 0; it < 2; ++it) {
        const int l = tid + it * 256;
        a_r[it] = l >> 3;                        // row in tile (0..63)
        a_c[it] = (l & 7) * 4;                   // k offset within 32-k tile
        const int t = t0 + a_r[it];
        a_tv[it] = (t < Tc);
        a_lv[it] = (t < ntok);                   // row fully valid iff t < ntok
        a_src[it] = xb + (size_t)t * (STRIDEc * Dc);
    }

    float4  ra[2];
    ushort8 rb[8];

    // ---- prologue loads (k0 = 0) ----
#pragma unroll
    for (int it = 0; it < 2; ++it) {
        ra[it] = make_float4(0.f, 0.f, 0.f, 0.f);
        if (a_lv[it]) ra[it] = *(const float4*)(a_src[it] + a_c[it]);
    }
#pragma unroll
    for (int it = 0; it < 8; ++it)
        rb[it] = *(const ushort8*)(Wt + (size_t)(tid + it * 256) * 8);

    for (int step = 0; step < 16; ++step) {
        const int k0 = step * 32;
        if (step) __syncthreads();               // previous MFMA reads done

        // ---- commit staged regs to LDS (LDS only; stores moved post-barrier) ----
#pragma unroll
        for (int it = 0; it < 2; ++it) {
            const float4 v = ra[it];
            ushort4 h4;
            h4.x = f2bf(v.x); h4.y = f2bf(v.y); h4.z = f2bf(v.z); h4.w = f2bf(v.w);
            *(ushort4*)(As + a_r[it] * PITCH + a_c[it]) = h4;
        }
#pragma unroll
        for (int it = 0; it < 8; ++it) {
            const int cc = tid + it * 256;
            *(ushort8*)(Bs + (cc >> 2) * PITCH + (cc & 3) * 8) = rb[it];
        }
        __syncthreads();

        // ---- tokens out (post-barrier: drain slack = prefetch + MFMA) ----
#pragma unroll
        for (int it = 0; it < 2; ++it) {
            if (a_tv[it])
                *(float4*)(tokb + (size_t)(t0 + a_r[it]) * Kc + k0 + a_c[it]) = ra[it];
        }

        // ---- prefetch next tile while MFMA runs ----
        if (step < 15) {
            const int kn = k0 + 32;
#pragma unroll
            for (int it = 0; it < 2; ++it) {
                ra[it] = make_float4(0.f, 0.f, 0.f, 0.f);
                if (a_lv[it]) ra[it] = *(const float4*)(a_src[it] + kn + a_c[it]);
            }
            const unsigned short* wsrc = Wt + (size_t)(step + 1) * (Hc * 32);
#pragma unroll
            for (int it = 0; it < 8; ++it)
                rb[it] = *(const ushort8*)(wsrc + (size_t)(tid + it * 256) * 8);
        }

        // ---- MFMA (operand-swapped); dead tt-subtiles skipped exactly ----
        if (ttmax == 4) {
            bf16x8 btok[4];
#pragma unroll
            for (int tt = 0; tt < 4; ++tt)
                btok[tt] = __builtin_bit_cast(bf16x8,
                    *(const ushort8*)(As + (tt * 16 + l15) * PITCH + quad * 8));
#pragma unroll
            for (int ct = 0; ct < 8; ++ct) {
                bf16x8 aW = __builtin_bit_cast(bf16x8,
                    *(const ushort8*)(Bs + (w * 128 + ct * 16 + l15) * PITCH + quad * 8));
#pragma unroll
                for (int tt = 0; tt < 4; ++tt)
                    acc[tt][ct] = __builtin_amdgcn_mfma_f32_16x16x32_bf16(
                        aW, btok[tt], acc[tt][ct], 0, 0, 0);
            }
        } else {
            bf16x8 btok[4] = {};
#pragma unroll
            for (int tt = 0; tt < 4; ++tt)
                if (tt < ttmax)
                    btok[tt] = __builtin_bit_cast(bf16x8,
                        *(const ushort8*)(As + (tt * 16 + l15) * PITCH + quad * 8));
#pragma unroll
            for (int ct = 0; ct < 8; ++ct) {
                bf16x8 aW = __builtin_bit_cast(bf16x8,
                    *(const ushort8*)(Bs + (w * 128 + ct * 16 + l15) * PITCH + quad * 8));
#pragma unroll
                for (int tt = 0; tt < 4; ++tt)
                    if (tt < ttmax)
                        acc[tt][ct] = __builtin_amdgcn_mfma_f32_16x16x32_bf16(
                            aW, btok[tt], acc[tt][ct], 0, 0, 0);
            }
        }
    }

    // ---- epilogue: bias, in-register row sums, RMS, scale, float4 stores ----
    float ss[4] = {0.f, 0.f, 0.f, 0.f};
#pragma unroll
    for (int ct = 0; ct < 8; ++ct) {
        const f32x4 b4 = *(const f32x4*)(bias + w * 128 + ct * 16 + quad * 4);
#pragma unroll
        for (int tt = 0; tt < 4; ++tt) {
            f32x4 h = acc[tt][ct] + b4;
            acc[tt][ct] = h;
            ss[tt] += h[0] * h[0] + h[1] * h[1] + h[2] * h[2] + h[3] * h[3];
        }
    }
#pragma unroll
    for (int tt = 0; tt < 4; ++tt) {
        float s = ss[tt];
        s += __shfl_xor(s, 16);
        s += __shfl_xor(s, 32);
        if (quad == 0) ssbuf[w][tt * 16 + l15] = s;
    }
    __syncthreads();
    float rstd[4];
#pragma unroll
    for (int tt = 0; tt < 4; ++tt) {
        const int r = tt * 16 + l15;
        const float tot = ssbuf[0][r] + ssbuf[1][r] + ssbuf[2][r] + ssbuf[3][r];
        rstd[tt] = rsqrtf(tot * (1.0f / (float)Hc) + EPSc);
    }
#pragma unroll
    for (int ct = 0; ct < 8; ++ct) {
        const f32x4 s4 = *(const f32x4*)(scale + w * 128 + ct * 16 + quad * 4);
#pragma unroll
        for (int tt = 0; tt < 4; ++tt) {
            const int t = t0 + tt * 16 + l15;
            if (t < Tc) {
                f32x4 o = acc[tt][ct] * rstd[tt] * s4;
                *(f32x4*)(hidden + ((size_t)b * Tc + t) * Hc
                          + w * 128 + ct * 16 + quad * 4) = o;
            }
        }
    }
}

extern "C" void kernel_launch(void* const* d_in, const int* in_sizes, int n_in,
                              void* d_out, int out_size, void* d_ws, size_t ws_size,
                              hipStream_t stream) {
    const float* x       = (const float*)d_in[0];
    const int*   lengths = (const int*)d_in[1];
    const float* W       = (const float*)d_in[2];
    const float* bias    = (const float*)d_in[3];
    const float* scale   = (const float*)d_in[4];

    const size_t BTH = (size_t)Bc * Tc * Hc;   // 16,760,832
    float* out    = (float*)d_out;
    float* hidden = out;                        // output 0
    float* tl     = out + BTH;                  // output 1 (32 floats)
    float* tokens = out + BTH + Bc;             // output 2

    // workspace layout: Wt (512 KB) | sched (512 ints)
    unsigned short* Wt = (unsigned short*)d_ws;
    int* sched = (int*)((char*)d_ws + WT_BYTES);

    {   // W -> Wt, token_lengths, cost-balanced tile schedule
        dim3 grid(Hc / 32, Hc / 32);            // (16,16)
        prep_kernel<<<grid, 256, 0, stream>>>(W, lengths, Wt, sched, tl);
    }
    {   // fused tokens + GEMM + RMSNorm (schedule-driven + row-proportional cost)
        dim3 grid(16, Bc);                      // 16 m-blocks x 32 batches
        fused_kernel<<<grid, 256, 0, stream>>>(x, lengths, Wt, bias, scale,
                                               sched, hidden, tokens);
    }
}

// Round 7
// 188.370 us; speedup vs baseline: 1.7903x; 1.7903x over previous
//
#include <hip/hip_runtime.h>
#include <hip/hip_bf16.h>

// Problem constants
constexpr int Bc = 32, Sc = 4096, Dc = 64, Pc = 8, STRIDEc = 4, Hc = 512;
constexpr int Tc = (Sc - Pc) / STRIDEc + 1;   // 1023
constexpr int Kc = Pc * Dc;                   // 512
constexpr float EPSc = 1e-6f;
constexpr int PITCH = 40;                     // bf16 LDS row pitch (80B -> 2-way banks = free)

typedef __bf16 bf16x8 __attribute__((ext_vector_type(8)));
typedef unsigned short ushort8 __attribute__((ext_vector_type(8)));
typedef float f32x4 __attribute__((ext_vector_type(4)));

__device__ __forceinline__ int n_tok_of(int len) {
    return (len >= Pc) ? ((len - Pc) / STRIDEc + 1) : 1;
}

// fp32 -> bf16 round-to-nearest-even
__device__ __forceinline__ unsigned short f2bf(float f) {
    unsigned u = __builtin_bit_cast(unsigned, f);
    u = (u + 0x7FFFu + ((u >> 16) & 1u)) >> 16;
    return (unsigned short)u;
}

// ---------------------------------------------------------------------------
// Prep: Wt_s[k0/32][n][k%32] = bf16(W[k][n])  (transposed, k-slice-packed so
// each k-step's B tile is one contiguous 32 KB block), + token_lengths.
// grid (16,16) tiles of 32x32, 256 threads.
// ---------------------------------------------------------------------------
__global__ __launch_bounds__(256) void prep_kernel(
        const float* __restrict__ W, const int* __restrict__ lengths,
        unsigned short* __restrict__ Wt, float* __restrict__ out_tl) {
    __shared__ float tile[32][33];
    const int k0 = blockIdx.x * 32, n0 = blockIdx.y * 32;
    const int r = threadIdx.x >> 3, c = (threadIdx.x & 7) * 4;
    const float4 v = *(const float4*)(W + (size_t)(k0 + r) * Hc + n0 + c);
    tile[c + 0][r] = v.x;
    tile[c + 1][r] = v.y;
    tile[c + 2][r] = v.z;
    tile[c + 3][r] = v.w;
    __syncthreads();
    ushort4 o;
    o.x = f2bf(tile[r][c + 0]);
    o.y = f2bf(tile[r][c + 1]);
    o.z = f2bf(tile[r][c + 2]);
    o.w = f2bf(tile[r][c + 3]);
    // slice = blockIdx.x; within slice: n-major, 32 k's per row
    *(ushort4*)(Wt + (size_t)blockIdx.x * (Hc * 32) + (size_t)(n0 + r) * 32 + c) = o;
    if (blockIdx.x == 0 && blockIdx.y == 0 && threadIdx.x < Bc)
        out_tl[threadIdx.x] = (float)n_tok_of(lengths[threadIdx.x]);
}

// ---------------------------------------------------------------------------
// Fused: tokens-write + bf16-MFMA GEMM (BM=64 x BN=512) + bias + RMSNorm*scale.
// EXACT r0 structure (best measured): B staged through LDS, tokens stores
// spread across the k-loop IN the commit phase (pre-barrier: this placement
// is load-bearing for write-combining -- moving them post-barrier in r6 gave
// 3.2x HBM write amplification), 2 barriers/step, software-pipelined.
// Deltas vs r0 (validated in r4, best normalized run):
//  * Balanced static tile remap: t0 = (b&16 ? 15-bx : bx)*64. Blocks (bx,b)
//    and (bx,b+16) share a CU; remap gives that CU one mostly-heavy + one
//    mostly-light tile instead of two identical-bx tiles (makespan 2H -> H+L).
//  * All-padding fast path (t0 >= ntok): hidden = scale*b/rms(b), tokens = 0.
//  * Dead per-element mask removed: t < ntok implies pos < len (len >= P).
// ---------------------------------------------------------------------------
__global__ __launch_bounds__(256, 2) void fused_kernel(
        const float* __restrict__ x, const int* __restrict__ lengths,
        const unsigned short* __restrict__ Wt, const float* __restrict__ bias,
        const float* __restrict__ scale, float* __restrict__ hidden,
        float* __restrict__ tokens) {
    const int b  = blockIdx.y;
    const int t0 = ((b & 16) ? (15 - (int)blockIdx.x) : (int)blockIdx.x) * 64;
    const int len = lengths[b];
    const int ntok = n_tok_of(len);
    const int tid = threadIdx.x;

    float* tokb = tokens + (size_t)b * Tc * Kc;

    if (t0 >= ntok) {
        // ---- fast path: every row in this block is padding ----
        // hidden row = scale * b / rms(b)  (== GEMM path on zero rows)
        __shared__ float red[4];
        const int w = tid >> 6, lane = tid & 63;
        const float2 b2 = *(const float2*)(bias + tid * 2);
        float s = b2.x * b2.x + b2.y * b2.y;
#pragma unroll
        for (int off = 32; off; off >>= 1) s += __shfl_xor(s, off);
        if (lane == 0) red[w] = s;
        __syncthreads();
        const float rstd0 = rsqrtf((red[0] + red[1] + red[2] + red[3])
                                   * (1.0f / (float)Hc) + EPSc);
        const int c4 = (tid & 127) * 4;
        const f32x4 cvec = *(const f32x4*)(bias + c4) * rstd0
                         * *(const f32x4*)(scale + c4);
        const f32x4 z = {0.f, 0.f, 0.f, 0.f};
        float* hidb = hidden + ((size_t)b * Tc + t0) * Hc;
        float* tokp = tokb + (size_t)t0 * Kc;
        const int r0 = tid >> 7;                 // 0 or 1: two rows per pass
#pragma unroll 8
        for (int rr = r0; rr < 64; rr += 2) {
            if (t0 + rr < Tc) {
                __builtin_nontemporal_store(cvec, (f32x4*)(hidb + (size_t)rr * Hc + c4));
                __builtin_nontemporal_store(z,    (f32x4*)(tokp + (size_t)rr * Kc + c4));
            }
        }
        return;
    }

    __shared__ unsigned short As[64 * PITCH];    // As[r][k], bf16 (token tile)
    __shared__ unsigned short Bs[512 * PITCH];   // Bs[n][k], bf16 (Wt tile)
    __shared__ float ssbuf[4][64];

    const int w    = tid >> 6;
    const int lane = tid & 63;
    const int l15  = lane & 15;
    const int quad = lane >> 4;

    f32x4 acc[4][8];                             // [ttile][ctile]
#pragma unroll
    for (int tt = 0; tt < 4; ++tt)
#pragma unroll
        for (int ct = 0; ct < 8; ++ct) acc[tt][ct] = (f32x4){0.f, 0.f, 0.f, 0.f};

    const float* xb = x + (size_t)b * (Sc * Dc);

    // Per-thread staging coordinates (A: 2 float4 chunks; B: 8 ushort8 chunks)
    int   a_r[2], a_c[2];  bool a_tv[2], a_lv[2];  const float* a_src[2];
#pragma unroll
    for (int it = 0; it < 2; ++it) {
        const int l = tid + it * 256;
        a_r[it] = l >> 3;                        // row in tile (0..63)
        a_c[it] = (l & 7) * 4;                   // k offset within 32-k tile
        const int t = t0 + a_r[it];
        a_tv[it] = (t < Tc);
        a_lv[it] = (t < ntok);                   // row fully valid iff t < ntok
        a_src[it] = xb + (size_t)t * (STRIDEc * Dc);
    }

    float4  ra[2];
    ushort8 rb[8];

    // ---- prologue loads (k0 = 0) ----
#pragma unroll
    for (int it = 0; it < 2; ++it) {
        ra[it] = make_float4(0.f, 0.f, 0.f, 0.f);
        if (a_lv[it]) ra[it] = *(const float4*)(a_src[it] + a_c[it]);
    }
#pragma unroll
    for (int it = 0; it < 8; ++it)
        rb[it] = *(const ushort8*)(Wt + (size_t)(tid + it * 256) * 8);

    for (int step = 0; step < 16; ++step) {
        const int k0 = step * 32;
        if (step) __syncthreads();               // previous MFMA reads done

        // ---- commit staged regs to LDS (+ tokens out) ----
#pragma unroll
        for (int it = 0; it < 2; ++it) {
            const float4 v = ra[it];
            if (a_tv[it])
                *(float4*)(tokb + (size_t)(t0 + a_r[it]) * Kc + k0 + a_c[it]) = v;
            ushort4 h4;
            h4.x = f2bf(v.x); h4.y = f2bf(v.y); h4.z = f2bf(v.z); h4.w = f2bf(v.w);
            *(ushort4*)(As + a_r[it] * PITCH + a_c[it]) = h4;
        }
#pragma unroll
        for (int it = 0; it < 8; ++it) {
            const int cc = tid + it * 256;
            *(ushort8*)(Bs + (cc >> 2) * PITCH + (cc & 3) * 8) = rb[it];
        }
        __syncthreads();

        // ---- prefetch next tile while MFMA runs ----
        if (step < 15) {
            const int kn = k0 + 32;
#pragma unroll
            for (int it = 0; it < 2; ++it) {
                ra[it] = make_float4(0.f, 0.f, 0.f, 0.f);
                if (a_lv[it]) ra[it] = *(const float4*)(a_src[it] + kn + a_c[it]);
            }
            const unsigned short* wsrc = Wt + (size_t)(step + 1) * (Hc * 32);
#pragma unroll
            for (int it = 0; it < 8; ++it)
                rb[it] = *(const ushort8*)(wsrc + (size_t)(tid + it * 256) * 8);
        }

        // ---- MFMA (operand-swapped) ----
        bf16x8 btok[4];
#pragma unroll
        for (int tt = 0; tt < 4; ++tt)
            btok[tt] = __builtin_bit_cast(bf16x8,
                *(const ushort8*)(As + (tt * 16 + l15) * PITCH + quad * 8));
#pragma unroll
        for (int ct = 0; ct < 8; ++ct) {
            bf16x8 aW = __builtin_bit_cast(bf16x8,
                *(const ushort8*)(Bs + (w * 128 + ct * 16 + l15) * PITCH + quad * 8));
#pragma unroll
            for (int tt = 0; tt < 4; ++tt)
                acc[tt][ct] = __builtin_amdgcn_mfma_f32_16x16x32_bf16(
                    aW, btok[tt], acc[tt][ct], 0, 0, 0);
        }
    }

    // ---- epilogue: bias, in-register row sums, RMS, scale, float4 stores ----
    float ss[4] = {0.f, 0.f, 0.f, 0.f};
#pragma unroll
    for (int ct = 0; ct < 8; ++ct) {
        const f32x4 b4 = *(const f32x4*)(bias + w * 128 + ct * 16 + quad * 4);
#pragma unroll
        for (int tt = 0; tt < 4; ++tt) {
            f32x4 h = acc[tt][ct] + b4;
            acc[tt][ct] = h;
            ss[tt] += h[0] * h[0] + h[1] * h[1] + h[2] * h[2] + h[3] * h[3];
        }
    }
#pragma unroll
    for (int tt = 0; tt < 4; ++tt) {
        float s = ss[tt];
        s += __shfl_xor(s, 16);
        s += __shfl_xor(s, 32);
        if (quad == 0) ssbuf[w][tt * 16 + l15] = s;
    }
    __syncthreads();
    float rstd[4];
#pragma unroll
    for (int tt = 0; tt < 4; ++tt) {
        const int r = tt * 16 + l15;
        const float tot = ssbuf[0][r] + ssbuf[1][r] + ssbuf[2][r] + ssbuf[3][r];
        rstd[tt] = rsqrtf(tot * (1.0f / (float)Hc) + EPSc);
    }
#pragma unroll
    for (int ct = 0; ct < 8; ++ct) {
        const f32x4 s4 = *(const f32x4*)(scale + w * 128 + ct * 16 + quad * 4);
#pragma unroll
        for (int tt = 0; tt < 4; ++tt) {
            const int t = t0 + tt * 16 + l15;
            if (t < Tc) {
                f32x4 o = acc[tt][ct] * rstd[tt] * s4;
                *(f32x4*)(hidden + ((size_t)b * Tc + t) * Hc
                          + w * 128 + ct * 16 + quad * 4) = o;
            }
        }
    }
}

extern "C" void kernel_launch(void* const* d_in, const int* in_sizes, int n_in,
                              void* d_out, int out_size, void* d_ws, size_t ws_size,
                              hipStream_t stream) {
    const float* x       = (const float*)d_in[0];
    const int*   lengths = (const int*)d_in[1];
    const float* W       = (const float*)d_in[2];
    const float* bias    = (const float*)d_in[3];
    const float* scale   = (const float*)d_in[4];

    const size_t BTH = (size_t)Bc * Tc * Hc;   // 16,760,832
    float* out    = (float*)d_out;
    float* hidden = out;                        // output 0
    float* tl     = out + BTH;                  // output 1 (32 floats)
    float* tokens = out + BTH + Bc;             // output 2

    unsigned short* Wt = (unsigned short*)d_ws; // 512x512 bf16 = 512 KB, k-slice-packed

    {   // W -> Wt (transpose + bf16 + slice-pack) and token_lengths
        dim3 grid(Hc / 32, Hc / 32);            // (16,16)
        prep_kernel<<<grid, 256, 0, stream>>>(W, lengths, Wt, tl);
    }
    {   // fused tokens + GEMM + RMSNorm (balanced static tiles + fast path)
        dim3 grid(16, Bc);                      // 16 m-blocks x 32 batches
        fused_kernel<<<grid, 256, 0, stream>>>(x, lengths, Wt, bias, scale,
                                               hidden, tokens);
    }
}